// Round 7
// baseline (3263.573 us; speedup 1.0000x reference)
//
#include <hip/hip_runtime.h>

// RGCN 2-layer graph encoder — R7: dst-exclusive LDS-accumulate, chain-free A-side.
//  - edges counting-sorted by key=(dst/48, rel); buckets padded to 32 slots
//  - scatter writes PERMUTED STREAMS psrc/pdst/einv -> edge kernel reads them
//    sequentially; only ONE random access remains (hb row gather), prefetched
//  - 32x32x16 MFMA tiles (32 edges): halves per-edge B traffic from L2
//  - block owns 48 dst nodes exclusively -> LDS accumulate, no global atomics

#define N_NODES 50000
#define N_EDGES 1200000
#define N_REL   40
#define N_BASES 30
#define EMB     64
#define HID     128
#define N_GRAPHS 64

#define DBLK    48
#define NDBLK   ((N_NODES + DBLK - 1) / DBLK)   // 1042
#define NKEY    (NDBLK * N_REL)                 // 41680
#define PERM_CAP ((size_t)N_EDGES + (size_t)NKEY * 31)
#define TILE_CAP (PERM_CAP / 32 + 64)

typedef float f32x4  __attribute__((ext_vector_type(4)));
typedef float f32x16 __attribute__((ext_vector_type(16)));
typedef short bf16x8 __attribute__((ext_vector_type(8)));

__device__ __forceinline__ unsigned short f2bf(float x) {
    unsigned int u = __float_as_uint(x);
    u = (u + 0x7FFFu + ((u >> 16) & 1u)) >> 16;   // RNE
    return (unsigned short)u;
}
__device__ __forceinline__ int dblk_of(int d) { return d / DBLK; }

// ---------------- workspace layout (float units) ----------------
#define OFF_WF1   ((size_t)0)                            // R*EMB*HID bf16
#define OFF_WF2   (OFF_WF1 + (size_t)N_REL*EMB*HID/2)
#define OFF_CNT   (OFF_WF2 + (size_t)N_REL*HID*HID/2)    // N*R f32
#define OFF_H1    (OFF_CNT + (size_t)N_NODES*N_REL)
#define OFF_H2    (OFF_H1 + (size_t)N_NODES*HID)
#define OFF_HB1   (OFF_H2 + (size_t)N_NODES*HID)         // N*EMB bf16
#define OFF_HB2   (OFF_HB1 + (size_t)N_NODES*EMB/2)      // N*HID bf16
#define OFF_CNTG  (OFF_HB2 + (size_t)N_NODES*HID/2)
#define OFF_POOL  (OFF_CNTG + N_GRAPHS)
#define OFF_PSRC  (OFF_POOL + (size_t)N_GRAPHS*HID)      // PERM_CAP ints
#define OFF_PDST  (OFF_PSRC + PERM_CAP)                  // PERM_CAP ints
#define OFF_EINV  (OFF_PDST + PERM_CAP)                  // PERM_CAP floats
#define OFF_HIST  (OFF_EINV + PERM_CAP)                  // NKEY ints
#define OFF_CUR   (OFF_HIST + NKEY)                      // NKEY ints
#define OFF_PO    (OFF_CUR + NKEY)                       // NKEY+1 ints
#define OFF_TREL  (OFF_PO + NKEY + 64)                   // TILE_CAP bytes

// ---- W fragment generator for 32x32x16 MFMA:
// Wf[r][((ct*KB+kb)*64+lane)*8+j] = W_r[kb*16+(lane>>5)*8+j][ct*32+(lane&31)]
template <int IN, int KB>
__global__ void k_Wfrag(const float* __restrict__ comp, const float* __restrict__ basis,
                        unsigned short* __restrict__ Wf) {
    const int FR = IN * HID;
    int idx = blockIdx.x * blockDim.x + threadIdx.x;
    if (idx >= N_REL * FR) return;
    int r = idx / FR, F = idx - r * FR;
    int j = F & 7, lane = (F >> 3) & 63, tt = F >> 9;
    int kb = tt % KB, ct = tt / KB;
    int k = kb * 16 + (lane >> 5) * 8 + j;
    int c = ct * 32 + (lane & 31);
    float s = 0.f;
#pragma unroll
    for (int b = 0; b < N_BASES; ++b)
        s += comp[r * N_BASES + b] * basis[((size_t)b * IN + k) * HID + c];
    Wf[idx] = f2bf(s);
}

__global__ void k_count(const int* __restrict__ dst, const int* __restrict__ etype,
                        float* __restrict__ cnt) {
    int e = blockIdx.x * blockDim.x + threadIdx.x;
    if (e >= N_EDGES) return;
    atomicAdd(&cnt[(size_t)dst[e] * N_REL + etype[e]], 1.0f);
}

// ---- (dst_block, rel) bucketing ----
__global__ void k_hist2(const int* __restrict__ dst, const int* __restrict__ etype,
                        int* __restrict__ hist) {
    int e = blockIdx.x * blockDim.x + threadIdx.x;
    if (e >= N_EDGES) return;
    atomicAdd(&hist[dblk_of(dst[e]) * N_REL + etype[e]], 1);
}

// single-block scan over NKEY buckets, padding each to a multiple of 32
__global__ void k_scan2(const int* __restrict__ hist, int* __restrict__ po) {
    __shared__ int csum[256];
    int t = threadIdx.x;
    const int CH = (NKEY + 255) / 256;
    int k0 = t * CH, k1 = min(k0 + CH, NKEY);
    int s = 0;
    for (int k = k0; k < k1; ++k) s += ((hist[k] + 31) >> 5) << 5;
    csum[t] = s;
    __syncthreads();
    if (t == 0) {
        int acc = 0;
        for (int i = 0; i < 256; ++i) { int v = csum[i]; csum[i] = acc; acc += v; }
        po[NKEY] = acc;
    }
    __syncthreads();
    int base = csum[t];
    for (int k = k0; k < k1; ++k) {
        po[k] = base;
        base += ((hist[k] + 31) >> 5) << 5;
    }
}

// tile(32) -> relation byte table
__global__ void k_tilerel(const int* __restrict__ po, unsigned char* __restrict__ trel) {
    int k = blockIdx.x * blockDim.x + threadIdx.x;
    if (k >= NKEY) return;
    int t0 = po[k] >> 5, t1 = po[k + 1] >> 5;
    unsigned char r = (unsigned char)(k % N_REL);
    for (int t = t0; t < t1; ++t) trel[t] = r;
}

// scatter permuted STREAMS: src-id, dst-id, 1/cnt per slot (pads stay 0)
__global__ void k_scatter4(const int* __restrict__ src, const int* __restrict__ dst,
                           const int* __restrict__ etype, const float* __restrict__ cnt,
                           const int* __restrict__ po, int* __restrict__ cur,
                           int* __restrict__ psrc, int* __restrict__ pdst,
                           float* __restrict__ einv) {
    int e = blockIdx.x * blockDim.x + threadIdx.x;
    if (e >= N_EDGES) return;
    int d = dst[e], r = etype[e];
    int key = dblk_of(d) * N_REL + r;
    int slot = po[key] + atomicAdd(&cur[key], 1);
    psrc[slot] = src[e];
    pdst[slot] = d;
    einv[slot] = 1.0f / fmaxf(cnt[(size_t)d * N_REL + r], 1.0f);
}

// h_acc[n, o] = bias[o] + sum_i hin[row(n), i] * root[i, o]
template <int IN>
__global__ void k_root(const float* __restrict__ hin, const int* __restrict__ xmap,
                       const float* __restrict__ root, const float* __restrict__ bias,
                       float* __restrict__ hacc) {
    int n = blockIdx.x;
    int o = threadIdx.x;  // 128
    int row = xmap ? xmap[n] : n;
    const float* hr = hin + (size_t)row * IN;
    float s = bias[o];
#pragma unroll 8
    for (int i = 0; i < IN; ++i)
        s = fmaf(hr[i], root[i * HID + o], s);
    hacc[(size_t)n * HID + o] = s;
}

// ---- MFMA 32x32 edge kernel, block = 48 dst nodes, 4 waves ----
// A: lane l holds hb[psrc[t*32+(l&31)]][kb*16 + (l>>5)*8 + j]  (16B gather)
// B: fragment-ordered W from L2, contiguous 16B per lane
// C: lane l, reg i -> edge row (i&3)+8*(i>>2)+4*(l>>5), col (l&31)+ct*32
template <int IN, int KB, bool WRITE_HB>
__global__ __launch_bounds__(256, 3)
void k_edge6(const unsigned short* __restrict__ hb_in, const int* __restrict__ psrc,
             const int* __restrict__ pdst, const float* __restrict__ einv,
             const unsigned char* __restrict__ trel, const int* __restrict__ po,
             const unsigned short* __restrict__ Wf, float* __restrict__ h,
             unsigned short* __restrict__ hb_out) {
    __shared__ float accL[DBLK][HID + 4];
    int b = blockIdx.x;
    int tbase = po[b * N_REL] >> 5;
    int tend  = po[(b + 1) * N_REL] >> 5;
    int n0 = b * DBLK;

    for (int i = threadIdx.x; i < DBLK * (HID + 4) / 4; i += 256)
        ((f32x4*)&accL[0][0])[i] = (f32x4){0.f, 0.f, 0.f, 0.f};
    __syncthreads();

    int l = threadIdx.x & 63, wv = threadIdx.x >> 6;  // 4 waves
    int col = l & 31, h5 = l >> 5;

    int t = tbase + wv;
    int sv = 0, dl = 0;
    float iv = 0.f;
    if (t < tend) {
        int slot = t * 32 + col;
        sv = psrc[slot];
        dl = max(pdst[slot] - n0, 0);
        iv = einv[slot];
    }

    for (; t < tend; t += 4) {
        // A-gather for current tile (ids ready from previous iteration)
        bf16x8 a[KB];
        const unsigned short* hrow = hb_in + (size_t)sv * IN + h5 * 8;
#pragma unroll
        for (int kb = 0; kb < KB; ++kb)
            a[kb] = *(const bf16x8*)(hrow + kb * 16);

        // prefetch next ids (sequential streams -> L2)
        int tn = t + 4, svn = 0, dln = 0;
        float ivn = 0.f;
        if (tn < tend) {
            int slot = tn * 32 + col;
            svn = psrc[slot];
            dln = max(pdst[slot] - n0, 0);
            ivn = einv[slot];
        }

        int r = trel[t];
        const unsigned short* Wr = Wf + (size_t)r * (4 * KB * 64 * 8);

        f32x16 acc[4];
#pragma unroll
        for (int ct = 0; ct < 4; ++ct)
#pragma unroll
            for (int i = 0; i < 16; ++i) acc[ct][i] = 0.f;

#pragma unroll
        for (int ct = 0; ct < 4; ++ct) {
#pragma unroll
            for (int kb = 0; kb < KB; ++kb) {
                bf16x8 bb = *(const bf16x8*)(Wr + ((size_t)(ct * KB + kb) * 64 + l) * 8);
                acc[ct] = __builtin_amdgcn_mfma_f32_32x32x16_bf16(a[kb], bb, acc[ct], 0, 0, 0);
            }
        }

        // LDS merge: rows -> accL[dloc][ct*32+col], scaled by per-edge inv
#pragma unroll
        for (int i = 0; i < 16; ++i) {
            int row = (i & 3) + 8 * (i >> 2) + 4 * h5;
            int   dli = __shfl(dl, row);
            float ivi = __shfl(iv, row);
            float* base = &accL[dli][col];
            atomicAdd(base +  0, acc[0][i] * ivi);
            atomicAdd(base + 32, acc[1][i] * ivi);
            atomicAdd(base + 64, acc[2][i] * ivi);
            atomicAdd(base + 96, acc[3][i] * ivi);
        }

        sv = svn; dl = dln; iv = ivn;
    }
    __syncthreads();

    // epilogue: h = relu(h_root + acc); optional bf16 shadow (distinct buffer)
    for (int idx = threadIdx.x; idx < DBLK * (HID / 4); idx += 256) {
        int row = idx >> 5, c4 = (idx & 31) << 2;
        int n = n0 + row;
        if (n < N_NODES) {
            float* hp = h + (size_t)n * HID + c4;
            f32x4 v = *(const f32x4*)hp;
            f32x4 m = *(const f32x4*)&accL[row][c4];
            v.x = fmaxf(v.x + m.x, 0.f);
            v.y = fmaxf(v.y + m.y, 0.f);
            v.z = fmaxf(v.z + m.z, 0.f);
            v.w = fmaxf(v.w + m.w, 0.f);
            *(f32x4*)hp = v;
            if (WRITE_HB) {
                ushort4 o = {f2bf(v.x), f2bf(v.y), f2bf(v.z), f2bf(v.w)};
                *(ushort4*)(hb_out + (size_t)n * HID + c4) = o;
            }
        }
    }
}

// layer-1 A source: hb1[n][:] = bf16(node_emb[x[n]][:])
__global__ void k_cvt_emb(const float* __restrict__ emb, const int* __restrict__ x,
                          unsigned short* __restrict__ hb) {
    int idx = blockIdx.x * blockDim.x + threadIdx.x;
    if (idx >= N_NODES * (EMB / 4)) return;
    int n = idx / (EMB / 4), c4 = idx % (EMB / 4);
    int row = x[n];
    float4 v = *(const float4*)(emb + (size_t)row * EMB + c4 * 4);
    ushort4 o = {f2bf(v.x), f2bf(v.y), f2bf(v.z), f2bf(v.w)};
    *(ushort4*)(hb + (size_t)n * EMB + c4 * 4) = o;
}

__global__ void k_gcount2(const int* __restrict__ batch, float* __restrict__ cntG) {
    int g = threadIdx.x;
    if (g >= N_GRAPHS) return;
    int lo = 0, hi = N_NODES;
    while (lo < hi) { int m = (lo + hi) >> 1; if (batch[m] < g) lo = m + 1; else hi = m; }
    int lb0 = lo;
    lo = 0; hi = N_NODES;
    while (lo < hi) { int m = (lo + hi) >> 1; if (batch[m] < g + 1) lo = m + 1; else hi = m; }
    cntG[g] = (float)(lo - lb0);
}

__global__ void k_pool(const float* __restrict__ h, const int* __restrict__ batch,
                       float* __restrict__ acc) {
    const int CH = 512;
    int n0 = blockIdx.x * CH;
    int o = threadIdx.x;  // 128
    int nend = min(n0 + CH, N_NODES);
    if (n0 >= N_NODES) return;
    int curg = batch[n0];
    float run = 0.f;
    for (int n = n0; n < nend; ++n) {
        int g = batch[n];
        if (g != curg) {
            atomicAdd(&acc[(size_t)curg * HID + o], run);
            run = 0.f;
            curg = g;
        }
        run += h[(size_t)n * HID + o];
    }
    atomicAdd(&acc[(size_t)curg * HID + o], run);
}

__global__ void k_final(const float* __restrict__ acc, const float* __restrict__ cntG,
                        float* __restrict__ out) {
    int idx = blockIdx.x * blockDim.x + threadIdx.x;
    if (idx >= N_GRAPHS * HID) return;
    int g = idx >> 7;
    out[idx] = acc[idx] / fmaxf(cntG[g], 1.0f);
}

extern "C" void kernel_launch(void* const* d_in, const int* in_sizes, int n_in,
                              void* d_out, int out_size, void* d_ws, size_t ws_size,
                              hipStream_t stream) {
    const int*   x         = (const int*)d_in[0];
    const int*   edge_index= (const int*)d_in[1];
    const int*   etype     = (const int*)d_in[2];
    const int*   batch     = (const int*)d_in[3];
    const float* node_emb  = (const float*)d_in[4];
    const float* comp1     = (const float*)d_in[5];
    const float* basis1    = (const float*)d_in[6];
    const float* root1     = (const float*)d_in[7];
    const float* bias1     = (const float*)d_in[8];
    const float* comp2     = (const float*)d_in[9];
    const float* basis2    = (const float*)d_in[10];
    const float* root2     = (const float*)d_in[11];
    const float* bias2     = (const float*)d_in[12];
    float* out = (float*)d_out;

    const int* src = edge_index;
    const int* dst = edge_index + N_EDGES;

    float* ws = (float*)d_ws;
    unsigned short* Wf1 = (unsigned short*)(ws + OFF_WF1);
    unsigned short* Wf2 = (unsigned short*)(ws + OFF_WF2);
    float* cnt  = ws + OFF_CNT;
    float* h1   = ws + OFF_H1;
    float* h2   = ws + OFF_H2;
    unsigned short* hb1 = (unsigned short*)(ws + OFF_HB1);
    unsigned short* hb2 = (unsigned short*)(ws + OFF_HB2);
    float* cntG = ws + OFF_CNTG;
    float* pool = ws + OFF_POOL;
    int*   psrc = (int*)(ws + OFF_PSRC);
    int*   pdst = (int*)(ws + OFF_PDST);
    float* einv = ws + OFF_EINV;
    int*   hist = (int*)(ws + OFF_HIST);
    int*   cur  = (int*)(ws + OFF_CUR);
    int*   po   = (int*)(ws + OFF_PO);
    unsigned char* trel = (unsigned char*)(ws + OFF_TREL);

    hipMemsetAsync(cnt, 0, (size_t)N_NODES * N_REL * sizeof(float), stream);
    hipMemsetAsync(cntG, 0, (size_t)(N_GRAPHS + N_GRAPHS * HID) * sizeof(float), stream);
    hipMemsetAsync(hist, 0, (size_t)2 * NKEY * sizeof(int), stream);     // hist + cur
    hipMemsetAsync(psrc, 0, (size_t)3 * PERM_CAP * sizeof(int), stream); // psrc+pdst+einv

    // per (dst, rel) counts first (scatter folds 1/cnt into einv stream)
    k_count<<<(N_EDGES + 255) / 256, 256, 0, stream>>>(dst, etype, cnt);

    // (dst_block, rel) bucketing -> permuted streams
    k_hist2<<<(N_EDGES + 255) / 256, 256, 0, stream>>>(dst, etype, hist);
    k_scan2<<<1, 256, 0, stream>>>(hist, po);
    k_tilerel<<<(NKEY + 255) / 256, 256, 0, stream>>>(po, trel);
    k_scatter4<<<(N_EDGES + 255) / 256, 256, 0, stream>>>(src, dst, etype, cnt, po, cur,
                                                          psrc, pdst, einv);

    // fragment-ordered bf16 weights (32x32 layout)
    k_Wfrag<EMB, 4><<<(N_REL * EMB * HID + 255) / 256, 256, 0, stream>>>(comp1, basis1, Wf1);
    k_Wfrag<HID, 8><<<(N_REL * HID * HID + 255) / 256, 256, 0, stream>>>(comp2, basis2, Wf2);

    // ---- layer 1 ----
    k_cvt_emb<<<(N_NODES * (EMB / 4) + 255) / 256, 256, 0, stream>>>(node_emb, x, hb1);
    k_root<EMB><<<N_NODES, HID, 0, stream>>>(node_emb, x, root1, bias1, h1);
    k_edge6<EMB, 4, true><<<NDBLK, 256, 0, stream>>>(hb1, psrc, pdst, einv, trel, po,
                                                     Wf1, h1, hb2);

    // ---- layer 2 ----
    k_root<HID><<<N_NODES, HID, 0, stream>>>(h1, nullptr, root2, bias2, h2);
    k_edge6<HID, 8, false><<<NDBLK, 256, 0, stream>>>(hb2, psrc, pdst, einv, trel, po,
                                                      Wf2, h2, nullptr);

    // ---- global mean pool ----
    k_gcount2<<<1, 64, 0, stream>>>(batch, cntG);
    k_pool<<<(N_NODES + 511) / 512, HID, 0, stream>>>(h2, batch, pool);
    k_final<<<(N_GRAPHS * HID + 255) / 256, 256, 0, stream>>>(pool, cntG, out);
}

// Round 8
// 1349.735 us; speedup vs baseline: 2.4179x; 2.4179x over previous
//
#include <hip/hip_runtime.h>

// RGCN 2-layer graph encoder — R8: two-phase message materialization.
//  Phase A (k_msg): R3-proven rel-major MFMA (W_r in LDS, 256-edge blocks,
//    ~1200 blocks/chunk) computing msg = (h[src] @ W_r) * (1/cnt); PLAIN
//    256B bf16-row stores into pm at the edge's dst-major slot. No atomics.
//  Phase B (k_reduce): per-node wave streams its contiguous pm rows
//    (coalesced), f32 accumulate, + root, relu, write h (+ bf16 shadow).
//  pm processed in NCH=4 dst-chunks reusing one 80 MB buffer (ws ~176 MB).
//  Prep (once, serves both layers): cnt[(dst,rel)], dst-major prefix po_d,
//  (chunk,rel)-major padded buckets po_cr, per-slot streams ps_src/ps_os/ps_inv.

#define N_NODES 50000
#define N_EDGES 1200000
#define N_REL   40
#define N_BASES 30
#define EMB     64
#define HID     128
#define N_GRAPHS 64

#define NCH     4
#define CHN     (N_NODES / NCH)                 // 12500 nodes per chunk
#define CAPR    312500                          // pm rows per chunk (incl dump row)
#define NKEYC   (NCH * N_REL)                   // 160 (chunk,rel) buckets
#define PERM_CAP ((size_t)N_EDGES + (size_t)NKEYC * 256)
#define CAPB    1280                            // fixed phase-A grid per chunk

typedef float f32x4  __attribute__((ext_vector_type(4)));
typedef short bf16x8 __attribute__((ext_vector_type(8)));

__device__ __forceinline__ unsigned short f2bf(float x) {
    unsigned int u = __float_as_uint(x);
    u = (u + 0x7FFFu + ((u >> 16) & 1u)) >> 16;   // RNE
    return (unsigned short)u;
}
__device__ __forceinline__ float bflo(unsigned int u) { return __uint_as_float(u << 16); }
__device__ __forceinline__ float bfhi(unsigned int u) { return __uint_as_float(u & 0xffff0000u); }

// ---------------- workspace layout (float units) ----------------
#define OFF_WF1   ((size_t)0)                    // 163,840
#define OFF_WF2   ((size_t)163840)               // 327,680
#define OFF_CNT   ((size_t)491520)               // 2,000,000
#define OFF_H1    ((size_t)2491520)              // 6,400,000
#define OFF_H2    ((size_t)8891520)              // 6,400,000
#define OFF_HB1   ((size_t)15291520)             // 1,600,000
#define OFF_HB2   ((size_t)16891520)             // 3,200,000
#define OFF_CNTG  ((size_t)20091520)             // 64
#define OFF_POOL  ((size_t)20091584)             // 8,192
#define OFF_PSRC  ((size_t)20099776)             // PERM_CAP = 1,240,960
#define OFF_POS   ((size_t)21340736)
#define OFF_PINV  ((size_t)22581696)
#define OFF_HCR   ((size_t)23822656)             // 160
#define OFF_CCR   ((size_t)23822816)             // 160
#define OFF_POCR  ((size_t)23822976)             // 192 (161 used)
#define OFF_HD    ((size_t)23823168)             // 50,000
#define OFF_CD    ((size_t)23873168)             // 50,000
#define OFF_POD   ((size_t)23923168)             // 50,016 (50,001 used)
#define OFF_PM    ((size_t)23973184)             // 20,000,000 u32 -> end ~176 MB

// ---- W fragment generator (16x16x32 layout, R3-proven):
// Wf[r][((ct*KT+kt)*64+lane)*8+j] = W_r[kt*32+(lane>>4)*8+j][ct*16+(lane&15)]
template <int IN, int KT>
__global__ void k_Wfrag(const float* __restrict__ comp, const float* __restrict__ basis,
                        unsigned short* __restrict__ Wf) {
    const int FR = IN * HID;
    int idx = blockIdx.x * blockDim.x + threadIdx.x;
    if (idx >= N_REL * FR) return;
    int r = idx / FR, F = idx - r * FR;
    int j = F & 7, lane = (F >> 3) & 63, tt = F >> 9;
    int kt = tt % KT, ct = tt / KT;
    int k = kt * 32 + (lane >> 4) * 8 + j;
    int c = ct * 16 + (lane & 15);
    float s = 0.f;
#pragma unroll
    for (int b = 0; b < N_BASES; ++b)
        s += comp[r * N_BASES + b] * basis[((size_t)b * IN + k) * HID + c];
    Wf[idx] = f2bf(s);
}

__global__ void k_count(const int* __restrict__ dst, const int* __restrict__ etype,
                        float* __restrict__ cnt) {
    int e = blockIdx.x * blockDim.x + threadIdx.x;
    if (e >= N_EDGES) return;
    atomicAdd(&cnt[(size_t)dst[e] * N_REL + etype[e]], 1.0f);
}

__global__ void k_hist_d(const int* __restrict__ dst, int* __restrict__ hist) {
    int e = blockIdx.x * blockDim.x + threadIdx.x;
    if (e >= N_EDGES) return;
    atomicAdd(&hist[dst[e]], 1);
}

// exclusive scan over N_NODES entries (no padding), po_d[N]=E
__global__ void k_scan_d(const int* __restrict__ hist, int* __restrict__ po) {
    __shared__ int csum[256];
    int t = threadIdx.x;
    const int CH = (N_NODES + 255) / 256;
    int k0 = t * CH, k1 = min(k0 + CH, N_NODES);
    int s = 0;
    for (int k = k0; k < k1; ++k) s += hist[k];
    csum[t] = s;
    __syncthreads();
    if (t == 0) {
        int acc = 0;
        for (int i = 0; i < 256; ++i) { int v = csum[i]; csum[i] = acc; acc += v; }
        po[N_NODES] = acc;
    }
    __syncthreads();
    int base = csum[t];
    for (int k = k0; k < k1; ++k) { po[k] = base; base += hist[k]; }
}

// (chunk, rel) histogram with LDS aggregation
__global__ void k_hist_cr(const int* __restrict__ dst, const int* __restrict__ etype,
                          int* __restrict__ hist) {
    __shared__ int lh[NKEYC];
    int t = threadIdx.x;
    if (t < NKEYC) lh[t] = 0;
    __syncthreads();
    int e = blockIdx.x * blockDim.x + t;
    if (e < N_EDGES) atomicAdd(&lh[(dst[e] / CHN) * N_REL + etype[e]], 1);
    __syncthreads();
    if (t < NKEYC && lh[t]) atomicAdd(&hist[t], lh[t]);
}

// scan 160 buckets, each padded to a multiple of 256
__global__ void k_scan_cr(const int* __restrict__ hist, int* __restrict__ po) {
    if (threadIdx.x == 0) {
        int acc = 0;
        for (int k = 0; k < NKEYC; ++k) {
            po[k] = acc;
            acc += ((hist[k] + 255) >> 8) << 8;
        }
        po[NKEYC] = acc;
    }
}

// init streams: pads -> dump row with inv 0
__global__ void k_fill(int* __restrict__ ps_src, int* __restrict__ ps_os,
                       float* __restrict__ ps_inv) {
    for (size_t s = (size_t)blockIdx.x * blockDim.x + threadIdx.x; s < PERM_CAP;
         s += (size_t)gridDim.x * blockDim.x) {
        ps_src[s] = 0;
        ps_os[s] = CAPR - 1;   // dump row (never read by phase B)
        ps_inv[s] = 0.f;
    }
}

// block-aggregated scatter into (chunk,rel)-major slots + dst-major oslot
#define SP_EPB 1024
__global__ void k_scatter_s(const int* __restrict__ src, const int* __restrict__ dst,
                            const int* __restrict__ etype, const float* __restrict__ cnt,
                            const int* __restrict__ po_cr, int* __restrict__ cur_cr,
                            const int* __restrict__ po_d, int* __restrict__ cur_d,
                            int* __restrict__ ps_src, int* __restrict__ ps_os,
                            float* __restrict__ ps_inv) {
    __shared__ int lh[NKEYC], sbase[NKEYC];
    int t = threadIdx.x;  // 256
    if (t < NKEYC) lh[t] = 0;
    __syncthreads();
    int e0 = blockIdx.x * SP_EPB;
    int e_[4], key_[4];
#pragma unroll
    for (int i = 0; i < 4; ++i) {
        int e = e0 + t + i * 256;
        e_[i] = e;
        if (e < N_EDGES) {
            key_[i] = (dst[e] / CHN) * N_REL + etype[e];
            atomicAdd(&lh[key_[i]], 1);
        }
    }
    __syncthreads();
    if (t < NKEYC) { if (lh[t]) sbase[t] = atomicAdd(&cur_cr[t], lh[t]); lh[t] = 0; }
    __syncthreads();
#pragma unroll
    for (int i = 0; i < 4; ++i) {
        if (e_[i] < N_EDGES) {
            int e = e_[i], key = key_[i];
            int d = dst[e], r = etype[e];
            int p = atomicAdd(&lh[key], 1);
            int slot = po_cr[key] + sbase[key] + p;
            int os_g = po_d[d] + atomicAdd(&cur_d[d], 1);
            int os_l = os_g - po_d[(d / CHN) * CHN];   // chunk-local pm row
            ps_src[slot] = src[e];
            ps_os[slot] = os_l;
            ps_inv[slot] = 1.0f / fmaxf(cnt[(size_t)d * N_REL + r], 1.0f);
        }
    }
}

// h_acc[n, o] = bias[o] + sum_i hin[row(n), i] * root[i, o]
template <int IN>
__global__ void k_root(const float* __restrict__ hin, const int* __restrict__ xmap,
                       const float* __restrict__ root, const float* __restrict__ bias,
                       float* __restrict__ hacc) {
    int n = blockIdx.x;
    int o = threadIdx.x;  // 128
    int row = xmap ? xmap[n] : n;
    const float* hr = hin + (size_t)row * IN;
    float s = bias[o];
#pragma unroll 8
    for (int i = 0; i < IN; ++i)
        s = fmaf(hr[i], root[i * HID + o], s);
    hacc[(size_t)n * HID + o] = s;
}

// ---- Phase A: rel-major MFMA message kernel (R3 structure, plain stores) ----
// A: lane l holds hb[edge(l&15)][kt*32 + (l>>4)*8 + j]
// C: lane l, reg q -> edge row (l>>4)*4+q, col (l&15)+ct*16
// store: pm[os*64 + cp*16 + lrow] = pack(col lrow+32cp, col lrow+32cp+16)
template <int IN, int KT>
__global__ __launch_bounds__(256, 4)
void k_msg(const unsigned short* __restrict__ hb_in, const int* __restrict__ ps_src,
           const int* __restrict__ ps_os, const float* __restrict__ ps_inv,
           const int* __restrict__ po_cr,   // 41 entries for this chunk
           const unsigned short* __restrict__ Wf, unsigned int* __restrict__ pm) {
    __shared__ unsigned short Wl[8 * KT * 64 * 8];
    int slot0 = po_cr[0] + blockIdx.x * 256;
    if (slot0 >= po_cr[N_REL]) return;
    int r = 0;
    while (po_cr[r + 1] <= slot0) ++r;   // bucket of this block (<=40 scalar loads)

    {   // stage W_r fragments -> LDS
        const f32x4* Wg = (const f32x4*)(Wf + (size_t)r * (8 * KT * 64 * 8));
        f32x4* Wd = (f32x4*)Wl;
        for (int kk = threadIdx.x; kk < 8 * KT * 64; kk += 256) Wd[kk] = Wg[kk];
    }
    __syncthreads();

    int l = threadIdx.x & 63, wv = threadIdx.x >> 6;
    int lrow = l & 15, lk = l >> 4;

    for (int t = wv; t < 16; t += 4) {
        int slot = slot0 + t * 16 + lrow;
        int sv = ps_src[slot];
        int os = ps_os[slot];
        float inv = ps_inv[slot];

        bf16x8 a[KT];
        const unsigned short* hrow = hb_in + (size_t)sv * IN + lk * 8;
#pragma unroll
        for (int kt = 0; kt < KT; ++kt)
            a[kt] = *(const bf16x8*)(hrow + kt * 32);

        f32x4 acc[8];
#pragma unroll
        for (int ct = 0; ct < 8; ++ct) acc[ct] = (f32x4){0.f, 0.f, 0.f, 0.f};
#pragma unroll
        for (int ct = 0; ct < 8; ++ct) {
#pragma unroll
            for (int kt = 0; kt < KT; ++kt) {
                bf16x8 bb = *(const bf16x8*)(Wl + ((ct * KT + kt) * 64 + l) * 8);
                acc[ct] = __builtin_amdgcn_mfma_f32_16x16x32_bf16(a[kt], bb, acc[ct], 0, 0, 0);
            }
        }
        // scaled bf16-pack store: per (q,cp) one 64B line per 16-lane group
#pragma unroll
        for (int q = 0; q < 4; ++q) {
            int row = lk * 4 + q;
            int osq   = __shfl(os, row);
            float ivq = __shfl(inv, row);
            unsigned int* dp = pm + (size_t)osq * 64 + lrow;
#pragma unroll
            for (int cp = 0; cp < 4; ++cp) {
                unsigned int u = (unsigned int)f2bf(acc[2 * cp][q] * ivq)
                               | ((unsigned int)f2bf(acc[2 * cp + 1][q] * ivq) << 16);
                dp[cp * 16] = u;
            }
        }
    }
}

// ---- Phase B: dst-major streaming reduce ----
// dword p of a pm row holds cols A=(p&15)+32*(p>>4) (lo) and A+16 (hi)
template <bool WRITE_HB>
__global__ __launch_bounds__(256, 8)
void k_reduce(const unsigned int* __restrict__ pm, const int* __restrict__ po_d,
              int n0chunk, float* __restrict__ h, unsigned short* __restrict__ hb_out) {
    int wv = threadIdx.x >> 6, p = threadIdx.x & 63;
    int n = n0chunk + blockIdx.x * 4 + wv;
    if (n >= n0chunk + CHN) return;
    int pmbase = po_d[n0chunk];
    int b0 = po_d[n] - pmbase;
    int cn = po_d[n + 1] - pmbase - b0;
    float lo = 0.f, hi = 0.f;
    const unsigned int* rp = pm + (size_t)b0 * 64 + p;
    int k = 0;
    for (; k + 4 <= cn; k += 4) {
        unsigned int u0 = rp[0], u1 = rp[64], u2 = rp[128], u3 = rp[192];
        rp += 256;
        lo += bflo(u0) + bflo(u1) + bflo(u2) + bflo(u3);
        hi += bfhi(u0) + bfhi(u1) + bfhi(u2) + bfhi(u3);
    }
    for (; k < cn; ++k) {
        unsigned int u = rp[0];
        rp += 64;
        lo += bflo(u); hi += bfhi(u);
    }
    int cA = (p & 15) + 32 * (p >> 4);
    float* hp = h + (size_t)n * HID;
    float vA = fmaxf(hp[cA] + lo, 0.f);
    float vB = fmaxf(hp[cA + 16] + hi, 0.f);
    hp[cA] = vA;
    hp[cA + 16] = vB;
    if (WRITE_HB) {
        hb_out[(size_t)n * HID + cA] = f2bf(vA);
        hb_out[(size_t)n * HID + cA + 16] = f2bf(vB);
    }
}

// layer-1 A source: hb1[n][:] = bf16(node_emb[x[n]][:])
__global__ void k_cvt_emb(const float* __restrict__ emb, const int* __restrict__ x,
                          unsigned short* __restrict__ hb) {
    int idx = blockIdx.x * blockDim.x + threadIdx.x;
    if (idx >= N_NODES * (EMB / 4)) return;
    int n = idx / (EMB / 4), c4 = idx % (EMB / 4);
    int row = x[n];
    float4 v = *(const float4*)(emb + (size_t)row * EMB + c4 * 4);
    ushort4 o = {f2bf(v.x), f2bf(v.y), f2bf(v.z), f2bf(v.w)};
    *(ushort4*)(hb + (size_t)n * EMB + c4 * 4) = o;
}

__global__ void k_gcount2(const int* __restrict__ batch, float* __restrict__ cntG) {
    int g = threadIdx.x;
    if (g >= N_GRAPHS) return;
    int lo = 0, hi = N_NODES;
    while (lo < hi) { int m = (lo + hi) >> 1; if (batch[m] < g) lo = m + 1; else hi = m; }
    int lb0 = lo;
    lo = 0; hi = N_NODES;
    while (lo < hi) { int m = (lo + hi) >> 1; if (batch[m] < g + 1) lo = m + 1; else hi = m; }
    cntG[g] = (float)(lo - lb0);
}

__global__ void k_pool(const float* __restrict__ h, const int* __restrict__ batch,
                       float* __restrict__ acc) {
    const int CH = 512;
    int n0 = blockIdx.x * CH;
    int o = threadIdx.x;  // 128
    int nend = min(n0 + CH, N_NODES);
    if (n0 >= N_NODES) return;
    int curg = batch[n0];
    float run = 0.f;
    for (int n = n0; n < nend; ++n) {
        int g = batch[n];
        if (g != curg) {
            atomicAdd(&acc[(size_t)curg * HID + o], run);
            run = 0.f;
            curg = g;
        }
        run += h[(size_t)n * HID + o];
    }
    atomicAdd(&acc[(size_t)curg * HID + o], run);
}

__global__ void k_final(const float* __restrict__ acc, const float* __restrict__ cntG,
                        float* __restrict__ out) {
    int idx = blockIdx.x * blockDim.x + threadIdx.x;
    if (idx >= N_GRAPHS * HID) return;
    int g = idx >> 7;
    out[idx] = acc[idx] / fmaxf(cntG[g], 1.0f);
}

extern "C" void kernel_launch(void* const* d_in, const int* in_sizes, int n_in,
                              void* d_out, int out_size, void* d_ws, size_t ws_size,
                              hipStream_t stream) {
    const int*   x         = (const int*)d_in[0];
    const int*   edge_index= (const int*)d_in[1];
    const int*   etype     = (const int*)d_in[2];
    const int*   batch     = (const int*)d_in[3];
    const float* node_emb  = (const float*)d_in[4];
    const float* comp1     = (const float*)d_in[5];
    const float* basis1    = (const float*)d_in[6];
    const float* root1     = (const float*)d_in[7];
    const float* bias1     = (const float*)d_in[8];
    const float* comp2     = (const float*)d_in[9];
    const float* basis2    = (const float*)d_in[10];
    const float* root2     = (const float*)d_in[11];
    const float* bias2     = (const float*)d_in[12];
    float* out = (float*)d_out;

    const int* src = edge_index;
    const int* dst = edge_index + N_EDGES;

    float* ws = (float*)d_ws;
    unsigned short* Wf1 = (unsigned short*)(ws + OFF_WF1);
    unsigned short* Wf2 = (unsigned short*)(ws + OFF_WF2);
    float* cnt  = ws + OFF_CNT;
    float* h1   = ws + OFF_H1;
    float* h2   = ws + OFF_H2;
    unsigned short* hb1 = (unsigned short*)(ws + OFF_HB1);
    unsigned short* hb2 = (unsigned short*)(ws + OFF_HB2);
    float* cntG = ws + OFF_CNTG;
    float* pool = ws + OFF_POOL;
    int*   ps_src = (int*)(ws + OFF_PSRC);
    int*   ps_os  = (int*)(ws + OFF_POS);
    float* ps_inv = ws + OFF_PINV;
    int*   hist_cr = (int*)(ws + OFF_HCR);
    int*   cur_cr  = (int*)(ws + OFF_CCR);
    int*   po_cr   = (int*)(ws + OFF_POCR);
    int*   hist_d  = (int*)(ws + OFF_HD);
    int*   cur_d   = (int*)(ws + OFF_CD);
    int*   po_d    = (int*)(ws + OFF_POD);
    unsigned int* pm = (unsigned int*)(ws + OFF_PM);

    hipMemsetAsync(cnt, 0, (size_t)N_NODES * N_REL * sizeof(float), stream);
    hipMemsetAsync(cntG, 0, (size_t)(N_GRAPHS + N_GRAPHS * HID) * sizeof(float), stream);
    hipMemsetAsync(hist_cr, 0, 2 * NKEYC * sizeof(int), stream);        // hist_cr + cur_cr
    hipMemsetAsync(hist_d, 0, 2 * N_NODES * sizeof(int), stream);       // hist_d + cur_d

    // ---- prep (serves both layers) ----
    k_count<<<(N_EDGES + 255) / 256, 256, 0, stream>>>(dst, etype, cnt);
    k_hist_d<<<(N_EDGES + 255) / 256, 256, 0, stream>>>(dst, hist_d);
    k_scan_d<<<1, 256, 0, stream>>>(hist_d, po_d);
    k_hist_cr<<<(N_EDGES + 255) / 256, 256, 0, stream>>>(dst, etype, hist_cr);
    k_scan_cr<<<1, 64, 0, stream>>>(hist_cr, po_cr);
    k_fill<<<2048, 256, 0, stream>>>(ps_src, ps_os, ps_inv);
    k_scatter_s<<<(N_EDGES + SP_EPB - 1) / SP_EPB, 256, 0, stream>>>(
        src, dst, etype, cnt, po_cr, cur_cr, po_d, cur_d, ps_src, ps_os, ps_inv);

    // fragment-ordered bf16 weights
    k_Wfrag<EMB, 2><<<(N_REL * EMB * HID + 255) / 256, 256, 0, stream>>>(comp1, basis1, Wf1);
    k_Wfrag<HID, 4><<<(N_REL * HID * HID + 255) / 256, 256, 0, stream>>>(comp2, basis2, Wf2);

    // ---- layer 1 ----
    k_cvt_emb<<<(N_NODES * (EMB / 4) + 255) / 256, 256, 0, stream>>>(node_emb, x, hb1);
    k_root<EMB><<<N_NODES, HID, 0, stream>>>(node_emb, x, root1, bias1, h1);
    for (int c = 0; c < NCH; ++c) {
        k_msg<EMB, 2><<<CAPB, 256, 0, stream>>>(hb1, ps_src, ps_os, ps_inv,
                                                po_cr + c * N_REL, Wf1, pm);
        k_reduce<true><<<CHN / 4, 256, 0, stream>>>(pm, po_d, c * CHN, h1, hb2);
    }

    // ---- layer 2 ----
    k_root<HID><<<N_NODES, HID, 0, stream>>>(h1, nullptr, root2, bias2, h2);
    for (int c = 0; c < NCH; ++c) {
        k_msg<HID, 4><<<CAPB, 256, 0, stream>>>(hb2, ps_src, ps_os, ps_inv,
                                                po_cr + c * N_REL, Wf2, pm);
        k_reduce<false><<<CHN / 4, 256, 0, stream>>>(pm, po_d, c * CHN, h2, nullptr);
    }

    // ---- global mean pool ----
    k_gcount2<<<1, 64, 0, stream>>>(batch, cntG);
    k_pool<<<(N_NODES + 511) / 512, HID, 0, stream>>>(h2, batch, pool);
    k_final<<<(N_GRAPHS * HID + 255) / 256, 256, 0, stream>>>(pool, cntG, out);
}

// Round 9
// 1038.965 us; speedup vs baseline: 3.1412x; 1.2991x over previous
//
#include <hip/hip_runtime.h>

// RGCN 2-layer graph encoder — R9: R8 two-phase structure + mid-kernel harvest.
//  Phase A (k_msg): rel-major MFMA (W_r in LDS), plain 256B bf16 stores into
//    pm at dst-major slots. Phase B (k_reduce): coalesced streaming reduce.
//  R9 deltas vs R8 (hot path untouched):
//   * k_root -> k_rootgemm: MFMA GEMM with LDS-staged fragment-ordered root
//   * k_pool: 64-node chunks (782 blocks, was 98)
//   * k_hist_d (1.2M atomics) -> k_deg (row-sum of cnt)

#define N_NODES 50000
#define N_EDGES 1200000
#define N_REL   40
#define N_BASES 30
#define EMB     64
#define HID     128
#define N_GRAPHS 64

#define NCH     4
#define CHN     (N_NODES / NCH)                 // 12500 nodes per chunk
#define CAPR    312500                          // pm rows per chunk (incl dump row)
#define NKEYC   (NCH * N_REL)                   // 160 (chunk,rel) buckets
#define PERM_CAP ((size_t)N_EDGES + (size_t)NKEYC * 256)
#define CAPB    1280                            // fixed phase-A grid per chunk

typedef float f32x4  __attribute__((ext_vector_type(4)));
typedef short bf16x8 __attribute__((ext_vector_type(8)));

__device__ __forceinline__ unsigned short f2bf(float x) {
    unsigned int u = __float_as_uint(x);
    u = (u + 0x7FFFu + ((u >> 16) & 1u)) >> 16;   // RNE
    return (unsigned short)u;
}
__device__ __forceinline__ float bflo(unsigned int u) { return __uint_as_float(u << 16); }
__device__ __forceinline__ float bfhi(unsigned int u) { return __uint_as_float(u & 0xffff0000u); }

// ---------------- workspace layout (float units) ----------------
#define OFF_WF1   ((size_t)0)                    // 163,840
#define OFF_WF2   ((size_t)163840)               // 327,680
#define OFF_CNT   ((size_t)491520)               // 2,000,000
#define OFF_H1    ((size_t)2491520)              // 6,400,000
#define OFF_H2    ((size_t)8891520)              // 6,400,000
#define OFF_HB1   ((size_t)15291520)             // 1,600,000
#define OFF_HB2   ((size_t)16891520)             // 3,200,000
#define OFF_CNTG  ((size_t)20091520)             // 64
#define OFF_POOL  ((size_t)20091584)             // 8,192
#define OFF_PSRC  ((size_t)20099776)             // PERM_CAP = 1,240,960
#define OFF_POS   ((size_t)21340736)
#define OFF_PINV  ((size_t)22581696)
#define OFF_HCR   ((size_t)23822656)             // 160
#define OFF_CCR   ((size_t)23822816)             // 160
#define OFF_POCR  ((size_t)23822976)             // 192 (161 used)
#define OFF_HD    ((size_t)23823168)             // 50,000
#define OFF_CD    ((size_t)23873168)             // 50,000
#define OFF_POD   ((size_t)23923168)             // 50,016 (50,001 used)
#define OFF_PM    ((size_t)23973184)             // 20,000,000 u32
#define OFF_RF1   ((size_t)43973184)             // 4,096  (EMB*HID bf16)
#define OFF_RF2   ((size_t)43977280)             // 8,192  (HID*HID bf16)

// ---- W fragment generator (16x16x32 layout, R3-proven):
// Wf[r][((ct*KT+kt)*64+lane)*8+j] = W_r[kt*32+(lane>>4)*8+j][ct*16+(lane&15)]
template <int IN, int KT>
__global__ void k_Wfrag(const float* __restrict__ comp, const float* __restrict__ basis,
                        unsigned short* __restrict__ Wf) {
    const int FR = IN * HID;
    int idx = blockIdx.x * blockDim.x + threadIdx.x;
    if (idx >= N_REL * FR) return;
    int r = idx / FR, F = idx - r * FR;
    int j = F & 7, lane = (F >> 3) & 63, tt = F >> 9;
    int kt = tt % KT, ct = tt / KT;
    int k = kt * 32 + (lane >> 4) * 8 + j;
    int c = ct * 16 + (lane & 15);
    float s = 0.f;
#pragma unroll
    for (int b = 0; b < N_BASES; ++b)
        s += comp[r * N_BASES + b] * basis[((size_t)b * IN + k) * HID + c];
    Wf[idx] = f2bf(s);
}

// root matrix -> fragment order (same mapping, no basis combine)
template <int IN, int KT>
__global__ void k_rootfrag(const float* __restrict__ root, unsigned short* __restrict__ rf) {
    int idx = blockIdx.x * blockDim.x + threadIdx.x;
    if (idx >= IN * HID) return;
    int j = idx & 7, lane = (idx >> 3) & 63, tt = idx >> 9;
    int kt = tt % KT, ct = tt / KT;
    int k = kt * 32 + (lane >> 4) * 8 + j;
    int c = ct * 16 + (lane & 15);
    rf[idx] = f2bf(root[k * HID + c]);
}

__global__ void k_count(const int* __restrict__ dst, const int* __restrict__ etype,
                        float* __restrict__ cnt) {
    int e = blockIdx.x * blockDim.x + threadIdx.x;
    if (e >= N_EDGES) return;
    atomicAdd(&cnt[(size_t)dst[e] * N_REL + etype[e]], 1.0f);
}

// degree per node = row-sum of cnt (replaces 1.2M-atomic histogram)
__global__ void k_deg(const float* __restrict__ cnt, int* __restrict__ hist) {
    int n = blockIdx.x * blockDim.x + threadIdx.x;
    if (n >= N_NODES) return;
    float s = 0.f;
#pragma unroll 8
    for (int r = 0; r < N_REL; ++r) s += cnt[(size_t)n * N_REL + r];
    hist[n] = (int)(s + 0.5f);
}

// exclusive scan over N_NODES entries (no padding), po_d[N]=E
__global__ void k_scan_d(const int* __restrict__ hist, int* __restrict__ po) {
    __shared__ int csum[256];
    int t = threadIdx.x;
    const int CH = (N_NODES + 255) / 256;
    int k0 = t * CH, k1 = min(k0 + CH, N_NODES);
    int s = 0;
    for (int k = k0; k < k1; ++k) s += hist[k];
    csum[t] = s;
    __syncthreads();
    if (t == 0) {
        int acc = 0;
        for (int i = 0; i < 256; ++i) { int v = csum[i]; csum[i] = acc; acc += v; }
        po[N_NODES] = acc;
    }
    __syncthreads();
    int base = csum[t];
    for (int k = k0; k < k1; ++k) { po[k] = base; base += hist[k]; }
}

// (chunk, rel) histogram with LDS aggregation
__global__ void k_hist_cr(const int* __restrict__ dst, const int* __restrict__ etype,
                          int* __restrict__ hist) {
    __shared__ int lh[NKEYC];
    int t = threadIdx.x;
    if (t < NKEYC) lh[t] = 0;
    __syncthreads();
    int e = blockIdx.x * blockDim.x + t;
    if (e < N_EDGES) atomicAdd(&lh[(dst[e] / CHN) * N_REL + etype[e]], 1);
    __syncthreads();
    if (t < NKEYC && lh[t]) atomicAdd(&hist[t], lh[t]);
}

// scan 160 buckets, each padded to a multiple of 256
__global__ void k_scan_cr(const int* __restrict__ hist, int* __restrict__ po) {
    if (threadIdx.x == 0) {
        int acc = 0;
        for (int k = 0; k < NKEYC; ++k) {
            po[k] = acc;
            acc += ((hist[k] + 255) >> 8) << 8;
        }
        po[NKEYC] = acc;
    }
}

// init streams: pads -> dump row with inv 0
__global__ void k_fill(int* __restrict__ ps_src, int* __restrict__ ps_os,
                       float* __restrict__ ps_inv) {
    for (size_t s = (size_t)blockIdx.x * blockDim.x + threadIdx.x; s < PERM_CAP;
         s += (size_t)gridDim.x * blockDim.x) {
        ps_src[s] = 0;
        ps_os[s] = CAPR - 1;   // dump row (never read by phase B)
        ps_inv[s] = 0.f;
    }
}

// block-aggregated scatter into (chunk,rel)-major slots + dst-major oslot
#define SP_EPB 1024
__global__ void k_scatter_s(const int* __restrict__ src, const int* __restrict__ dst,
                            const int* __restrict__ etype, const float* __restrict__ cnt,
                            const int* __restrict__ po_cr, int* __restrict__ cur_cr,
                            const int* __restrict__ po_d, int* __restrict__ cur_d,
                            int* __restrict__ ps_src, int* __restrict__ ps_os,
                            float* __restrict__ ps_inv) {
    __shared__ int lh[NKEYC], sbase[NKEYC];
    int t = threadIdx.x;  // 256
    if (t < NKEYC) lh[t] = 0;
    __syncthreads();
    int e0 = blockIdx.x * SP_EPB;
    int e_[4], key_[4];
#pragma unroll
    for (int i = 0; i < 4; ++i) {
        int e = e0 + t + i * 256;
        e_[i] = e;
        if (e < N_EDGES) {
            key_[i] = (dst[e] / CHN) * N_REL + etype[e];
            atomicAdd(&lh[key_[i]], 1);
        }
    }
    __syncthreads();
    if (t < NKEYC) { if (lh[t]) sbase[t] = atomicAdd(&cur_cr[t], lh[t]); lh[t] = 0; }
    __syncthreads();
#pragma unroll
    for (int i = 0; i < 4; ++i) {
        if (e_[i] < N_EDGES) {
            int e = e_[i], key = key_[i];
            int d = dst[e], r = etype[e];
            int p = atomicAdd(&lh[key], 1);
            int slot = po_cr[key] + sbase[key] + p;
            int os_g = po_d[d] + atomicAdd(&cur_d[d], 1);
            int os_l = os_g - po_d[(d / CHN) * CHN];   // chunk-local pm row
            ps_src[slot] = src[e];
            ps_os[slot] = os_l;
            ps_inv[slot] = 1.0f / fmaxf(cnt[(size_t)d * N_REL + r], 1.0f);
        }
    }
}

// ---- MFMA root GEMM: h[n] = bias + hb[n] @ root  (plain f32 stores) ----
// A: lane l holds hb[nbase + (l&15)][kt*32 + (l>>4)*8 + j] (sequential rows)
// C: lane l, reg q -> row (l>>4)*4+q, col (l&15)+ct*16  (direct store, no shfl)
template <int IN, int KT>
__global__ __launch_bounds__(256, 4)
void k_rootgemm(const unsigned short* __restrict__ hb_in,
                const unsigned short* __restrict__ rf,
                const float* __restrict__ bias, float* __restrict__ h) {
    __shared__ unsigned short Wl[8 * KT * 64 * 8];
    {
        const f32x4* Wg = (const f32x4*)rf;
        f32x4* Wd = (f32x4*)Wl;
        for (int kk = threadIdx.x; kk < 8 * KT * 64; kk += 256) Wd[kk] = Wg[kk];
    }
    __syncthreads();

    int l = threadIdx.x & 63, wv = threadIdx.x >> 6;
    int lrow = l & 15, lk = l >> 4;
    int nbase = blockIdx.x * 64 + wv * 16;

    int nrow = min(nbase + lrow, N_NODES - 1);
    bf16x8 a[KT];
    const unsigned short* hrow = hb_in + (size_t)nrow * IN + lk * 8;
#pragma unroll
    for (int kt = 0; kt < KT; ++kt)
        a[kt] = *(const bf16x8*)(hrow + kt * 32);

    f32x4 acc[8];
#pragma unroll
    for (int ct = 0; ct < 8; ++ct) acc[ct] = (f32x4){0.f, 0.f, 0.f, 0.f};
#pragma unroll
    for (int ct = 0; ct < 8; ++ct) {
#pragma unroll
        for (int kt = 0; kt < KT; ++kt) {
            bf16x8 bb = *(const bf16x8*)(Wl + ((ct * KT + kt) * 64 + l) * 8);
            acc[ct] = __builtin_amdgcn_mfma_f32_16x16x32_bf16(a[kt], bb, acc[ct], 0, 0, 0);
        }
    }
#pragma unroll
    for (int q = 0; q < 4; ++q) {
        int n = nbase + lk * 4 + q;
        if (n < N_NODES) {
#pragma unroll
            for (int ct = 0; ct < 8; ++ct)
                h[(size_t)n * HID + ct * 16 + lrow] = acc[ct][q] + bias[ct * 16 + lrow];
        }
    }
}

// ---- Phase A: rel-major MFMA message kernel (plain stores) ----
template <int IN, int KT>
__global__ __launch_bounds__(256, 4)
void k_msg(const unsigned short* __restrict__ hb_in, const int* __restrict__ ps_src,
           const int* __restrict__ ps_os, const float* __restrict__ ps_inv,
           const int* __restrict__ po_cr,   // 41 entries for this chunk
           const unsigned short* __restrict__ Wf, unsigned int* __restrict__ pm) {
    __shared__ unsigned short Wl[8 * KT * 64 * 8];
    int slot0 = po_cr[0] + blockIdx.x * 256;
    if (slot0 >= po_cr[N_REL]) return;
    int r = 0;
    while (po_cr[r + 1] <= slot0) ++r;

    {   // stage W_r fragments -> LDS
        const f32x4* Wg = (const f32x4*)(Wf + (size_t)r * (8 * KT * 64 * 8));
        f32x4* Wd = (f32x4*)Wl;
        for (int kk = threadIdx.x; kk < 8 * KT * 64; kk += 256) Wd[kk] = Wg[kk];
    }
    __syncthreads();

    int l = threadIdx.x & 63, wv = threadIdx.x >> 6;
    int lrow = l & 15, lk = l >> 4;

    for (int t = wv; t < 16; t += 4) {
        int slot = slot0 + t * 16 + lrow;
        int sv = ps_src[slot];
        int os = ps_os[slot];
        float inv = ps_inv[slot];

        bf16x8 a[KT];
        const unsigned short* hrow = hb_in + (size_t)sv * IN + lk * 8;
#pragma unroll
        for (int kt = 0; kt < KT; ++kt)
            a[kt] = *(const bf16x8*)(hrow + kt * 32);

        f32x4 acc[8];
#pragma unroll
        for (int ct = 0; ct < 8; ++ct) acc[ct] = (f32x4){0.f, 0.f, 0.f, 0.f};
#pragma unroll
        for (int ct = 0; ct < 8; ++ct) {
#pragma unroll
            for (int kt = 0; kt < KT; ++kt) {
                bf16x8 bb = *(const bf16x8*)(Wl + ((ct * KT + kt) * 64 + l) * 8);
                acc[ct] = __builtin_amdgcn_mfma_f32_16x16x32_bf16(a[kt], bb, acc[ct], 0, 0, 0);
            }
        }
        // scaled bf16-pack store: per (q,cp) one 64B line per 16-lane group
#pragma unroll
        for (int q = 0; q < 4; ++q) {
            int row = lk * 4 + q;
            int osq   = __shfl(os, row);
            float ivq = __shfl(inv, row);
            unsigned int* dp = pm + (size_t)osq * 64 + lrow;
#pragma unroll
            for (int cp = 0; cp < 4; ++cp) {
                unsigned int u = (unsigned int)f2bf(acc[2 * cp][q] * ivq)
                               | ((unsigned int)f2bf(acc[2 * cp + 1][q] * ivq) << 16);
                dp[cp * 16] = u;
            }
        }
    }
}

// ---- Phase B: dst-major streaming reduce ----
template <bool WRITE_HB>
__global__ __launch_bounds__(256, 8)
void k_reduce(const unsigned int* __restrict__ pm, const int* __restrict__ po_d,
              int n0chunk, float* __restrict__ h, unsigned short* __restrict__ hb_out) {
    int wv = threadIdx.x >> 6, p = threadIdx.x & 63;
    int n = n0chunk + blockIdx.x * 4 + wv;
    if (n >= n0chunk + CHN) return;
    int pmbase = po_d[n0chunk];
    int b0 = po_d[n] - pmbase;
    int cn = po_d[n + 1] - pmbase - b0;
    float lo = 0.f, hi = 0.f;
    const unsigned int* rp = pm + (size_t)b0 * 64 + p;
    int k = 0;
    for (; k + 4 <= cn; k += 4) {
        unsigned int u0 = rp[0], u1 = rp[64], u2 = rp[128], u3 = rp[192];
        rp += 256;
        lo += bflo(u0) + bflo(u1) + bflo(u2) + bflo(u3);
        hi += bfhi(u0) + bfhi(u1) + bfhi(u2) + bfhi(u3);
    }
    for (; k < cn; ++k) {
        unsigned int u = rp[0];
        rp += 64;
        lo += bflo(u); hi += bfhi(u);
    }
    int cA = (p & 15) + 32 * (p >> 4);
    float* hp = h + (size_t)n * HID;
    float vA = fmaxf(hp[cA] + lo, 0.f);
    float vB = fmaxf(hp[cA + 16] + hi, 0.f);
    hp[cA] = vA;
    hp[cA + 16] = vB;
    if (WRITE_HB) {
        hb_out[(size_t)n * HID + cA] = f2bf(vA);
        hb_out[(size_t)n * HID + cA + 16] = f2bf(vB);
    }
}

// layer-1 A source: hb1[n][:] = bf16(node_emb[x[n]][:])
__global__ void k_cvt_emb(const float* __restrict__ emb, const int* __restrict__ x,
                          unsigned short* __restrict__ hb) {
    int idx = blockIdx.x * blockDim.x + threadIdx.x;
    if (idx >= N_NODES * (EMB / 4)) return;
    int n = idx / (EMB / 4), c4 = idx % (EMB / 4);
    int row = x[n];
    float4 v = *(const float4*)(emb + (size_t)row * EMB + c4 * 4);
    ushort4 o = {f2bf(v.x), f2bf(v.y), f2bf(v.z), f2bf(v.w)};
    *(ushort4*)(hb + (size_t)n * EMB + c4 * 4) = o;
}

__global__ void k_gcount2(const int* __restrict__ batch, float* __restrict__ cntG) {
    int g = threadIdx.x;
    if (g >= N_GRAPHS) return;
    int lo = 0, hi = N_NODES;
    while (lo < hi) { int m = (lo + hi) >> 1; if (batch[m] < g) lo = m + 1; else hi = m; }
    int lb0 = lo;
    lo = 0; hi = N_NODES;
    while (lo < hi) { int m = (lo + hi) >> 1; if (batch[m] < g + 1) lo = m + 1; else hi = m; }
    cntG[g] = (float)(lo - lb0);
}

// 64-node chunks -> 782 blocks (was 98): restores occupancy
__global__ void k_pool(const float* __restrict__ h, const int* __restrict__ batch,
                       float* __restrict__ acc) {
    const int CH = 64;
    int n0 = blockIdx.x * CH;
    int o = threadIdx.x;  // 128
    int nend = min(n0 + CH, N_NODES);
    if (n0 >= N_NODES) return;
    int curg = batch[n0];
    float run = 0.f;
    for (int n = n0; n < nend; ++n) {
        int g = batch[n];
        if (g != curg) {
            atomicAdd(&acc[(size_t)curg * HID + o], run);
            run = 0.f;
            curg = g;
        }
        run += h[(size_t)n * HID + o];
    }
    atomicAdd(&acc[(size_t)curg * HID + o], run);
}

__global__ void k_final(const float* __restrict__ acc, const float* __restrict__ cntG,
                        float* __restrict__ out) {
    int idx = blockIdx.x * blockDim.x + threadIdx.x;
    if (idx >= N_GRAPHS * HID) return;
    int g = idx >> 7;
    out[idx] = acc[idx] / fmaxf(cntG[g], 1.0f);
}

extern "C" void kernel_launch(void* const* d_in, const int* in_sizes, int n_in,
                              void* d_out, int out_size, void* d_ws, size_t ws_size,
                              hipStream_t stream) {
    const int*   x         = (const int*)d_in[0];
    const int*   edge_index= (const int*)d_in[1];
    const int*   etype     = (const int*)d_in[2];
    const int*   batch     = (const int*)d_in[3];
    const float* node_emb  = (const float*)d_in[4];
    const float* comp1     = (const float*)d_in[5];
    const float* basis1    = (const float*)d_in[6];
    const float* root1     = (const float*)d_in[7];
    const float* bias1     = (const float*)d_in[8];
    const float* comp2     = (const float*)d_in[9];
    const float* basis2    = (const float*)d_in[10];
    const float* root2     = (const float*)d_in[11];
    const float* bias2     = (const float*)d_in[12];
    float* out = (float*)d_out;

    const int* src = edge_index;
    const int* dst = edge_index + N_EDGES;

    float* ws = (float*)d_ws;
    unsigned short* Wf1 = (unsigned short*)(ws + OFF_WF1);
    unsigned short* Wf2 = (unsigned short*)(ws + OFF_WF2);
    float* cnt  = ws + OFF_CNT;
    float* h1   = ws + OFF_H1;
    float* h2   = ws + OFF_H2;
    unsigned short* hb1 = (unsigned short*)(ws + OFF_HB1);
    unsigned short* hb2 = (unsigned short*)(ws + OFF_HB2);
    float* cntG = ws + OFF_CNTG;
    float* pool = ws + OFF_POOL;
    int*   ps_src = (int*)(ws + OFF_PSRC);
    int*   ps_os  = (int*)(ws + OFF_POS);
    float* ps_inv = ws + OFF_PINV;
    int*   hist_cr = (int*)(ws + OFF_HCR);
    int*   cur_cr  = (int*)(ws + OFF_CCR);
    int*   po_cr   = (int*)(ws + OFF_POCR);
    int*   hist_d  = (int*)(ws + OFF_HD);
    int*   cur_d   = (int*)(ws + OFF_CD);
    int*   po_d    = (int*)(ws + OFF_POD);
    unsigned int* pm = (unsigned int*)(ws + OFF_PM);
    unsigned short* rf1 = (unsigned short*)(ws + OFF_RF1);
    unsigned short* rf2 = (unsigned short*)(ws + OFF_RF2);

    hipMemsetAsync(cnt, 0, (size_t)N_NODES * N_REL * sizeof(float), stream);
    hipMemsetAsync(cntG, 0, (size_t)(N_GRAPHS + N_GRAPHS * HID) * sizeof(float), stream);
    hipMemsetAsync(hist_cr, 0, 2 * NKEYC * sizeof(int), stream);        // hist_cr + cur_cr
    hipMemsetAsync(cur_d, 0, N_NODES * sizeof(int), stream);

    // ---- prep (serves both layers) ----
    k_count<<<(N_EDGES + 255) / 256, 256, 0, stream>>>(dst, etype, cnt);
    k_deg<<<(N_NODES + 255) / 256, 256, 0, stream>>>(cnt, hist_d);
    k_scan_d<<<1, 256, 0, stream>>>(hist_d, po_d);
    k_hist_cr<<<(N_EDGES + 255) / 256, 256, 0, stream>>>(dst, etype, hist_cr);
    k_scan_cr<<<1, 64, 0, stream>>>(hist_cr, po_cr);
    k_fill<<<2048, 256, 0, stream>>>(ps_src, ps_os, ps_inv);
    k_scatter_s<<<(N_EDGES + SP_EPB - 1) / SP_EPB, 256, 0, stream>>>(
        src, dst, etype, cnt, po_cr, cur_cr, po_d, cur_d, ps_src, ps_os, ps_inv);

    // fragment-ordered bf16 weights + root matrices
    k_Wfrag<EMB, 2><<<(N_REL * EMB * HID + 255) / 256, 256, 0, stream>>>(comp1, basis1, Wf1);
    k_Wfrag<HID, 4><<<(N_REL * HID * HID + 255) / 256, 256, 0, stream>>>(comp2, basis2, Wf2);
    k_rootfrag<EMB, 2><<<(EMB * HID + 255) / 256, 256, 0, stream>>>(root1, rf1);
    k_rootfrag<HID, 4><<<(HID * HID + 255) / 256, 256, 0, stream>>>(root2, rf2);

    // ---- layer 1 ----
    k_cvt_emb<<<(N_NODES * (EMB / 4) + 255) / 256, 256, 0, stream>>>(node_emb, x, hb1);
    k_rootgemm<EMB, 2><<<(N_NODES + 63) / 64, 256, 0, stream>>>(hb1, rf1, bias1, h1);
    for (int c = 0; c < NCH; ++c) {
        k_msg<EMB, 2><<<CAPB, 256, 0, stream>>>(hb1, ps_src, ps_os, ps_inv,
                                                po_cr + c * N_REL, Wf1, pm);
        k_reduce<true><<<CHN / 4, 256, 0, stream>>>(pm, po_d, c * CHN, h1, hb2);
    }

    // ---- layer 2 ----
    k_rootgemm<HID, 4><<<(N_NODES + 63) / 64, 256, 0, stream>>>(hb2, rf2, bias2, h2);
    for (int c = 0; c < NCH; ++c) {
        k_msg<HID, 4><<<CAPB, 256, 0, stream>>>(hb2, ps_src, ps_os, ps_inv,
                                                po_cr + c * N_REL, Wf2, pm);
        k_reduce<false><<<CHN / 4, 256, 0, stream>>>(pm, po_d, c * CHN, h2, nullptr);
    }

    // ---- global mean pool ----
    k_gcount2<<<1, 64, 0, stream>>>(batch, cntG);
    k_pool<<<(N_NODES + 63) / 64, HID, 0, stream>>>(h2, batch, pool);
    k_final<<<(N_GRAPHS * HID + 255) / 256, 256, 0, stream>>>(pool, cntG, out);
}

// Round 10
// 1030.560 us; speedup vs baseline: 3.1668x; 1.0082x over previous
//
#include <hip/hip_runtime.h>

// RGCN 2-layer graph encoder — R10: R9 two-phase structure +
//  * scatter no longer gathers cnt: k_deg_inv converts cnt -> 1/max(cnt,1)
//    IN PLACE; scatter emits ps_dst; k_msg gathers inv itself (hidden by MFMA)
//  * runtime-adaptive NCH in {1,2,4} chosen from ws_size (deterministic):
//    NCH=1 (~407 MB) removes 12 serialized chunk-drains; NCH=4 fallback has
//    R9's exact 176 MB footprint.

#define N_NODES 50000
#define N_EDGES 1200000
#define N_REL   40
#define N_BASES 30
#define EMB     64
#define HID     128
#define N_GRAPHS 64

#define NKEYC_MAX 160                                    // 4 chunks * 40 rels
#define PERM_CAP  ((size_t)N_EDGES + (size_t)NKEYC_MAX * 256)
#define SP_EPB    1024

typedef float f32x4  __attribute__((ext_vector_type(4)));
typedef short bf16x8 __attribute__((ext_vector_type(8)));

__device__ __forceinline__ unsigned short f2bf(float x) {
    unsigned int u = __float_as_uint(x);
    u = (u + 0x7FFFu + ((u >> 16) & 1u)) >> 16;   // RNE
    return (unsigned short)u;
}
__device__ __forceinline__ float bflo(unsigned int u) { return __uint_as_float(u << 16); }
__device__ __forceinline__ float bfhi(unsigned int u) { return __uint_as_float(u & 0xffff0000u); }

// ---------------- workspace layout (float units) ----------------
#define OFF_WF1   ((size_t)0)                    // 163,840
#define OFF_WF2   ((size_t)163840)               // 327,680
#define OFF_CNT   ((size_t)491520)               // 2,000,000 (cnt, then invcnt in place)
#define OFF_H1    ((size_t)2491520)              // 6,400,000
#define OFF_H2    ((size_t)8891520)              // 6,400,000
#define OFF_HB1   ((size_t)15291520)             // 1,600,000
#define OFF_HB2   ((size_t)16891520)             // 3,200,000
#define OFF_CNTG  ((size_t)20091520)             // 64
#define OFF_POOL  ((size_t)20091584)             // 8,192
#define OFF_PSRC  ((size_t)20099776)             // 1,240,960
#define OFF_POS   ((size_t)21340736)             // 1,240,960
#define OFF_PDST  ((size_t)22581696)             // 1,240,960
#define OFF_HCR   ((size_t)23822656)             // 160
#define OFF_CCR   ((size_t)23822816)             // 160
#define OFF_POCR  ((size_t)23822976)             // 192 (161 used)
#define OFF_HD    ((size_t)23823168)             // 50,000
#define OFF_CD    ((size_t)23873168)             // 50,000
#define OFF_POD   ((size_t)23923168)             // 50,016
#define OFF_RF1   ((size_t)23973184)             // 4,096
#define OFF_RF2   ((size_t)23977280)             // 8,192
#define OFF_PM    ((size_t)23985472)             // capr(nch) * 64

// ---- W fragment generator (16x16x32 layout):
// Wf[r][((ct*KT+kt)*64+lane)*8+j] = W_r[kt*32+(lane>>4)*8+j][ct*16+(lane&15)]
template <int IN, int KT>
__global__ void k_Wfrag(const float* __restrict__ comp, const float* __restrict__ basis,
                        unsigned short* __restrict__ Wf) {
    const int FR = IN * HID;
    int idx = blockIdx.x * blockDim.x + threadIdx.x;
    if (idx >= N_REL * FR) return;
    int r = idx / FR, F = idx - r * FR;
    int j = F & 7, lane = (F >> 3) & 63, tt = F >> 9;
    int kt = tt % KT, ct = tt / KT;
    int k = kt * 32 + (lane >> 4) * 8 + j;
    int c = ct * 16 + (lane & 15);
    float s = 0.f;
#pragma unroll
    for (int b = 0; b < N_BASES; ++b)
        s += comp[r * N_BASES + b] * basis[((size_t)b * IN + k) * HID + c];
    Wf[idx] = f2bf(s);
}

template <int IN, int KT>
__global__ void k_rootfrag(const float* __restrict__ root, unsigned short* __restrict__ rf) {
    int idx = blockIdx.x * blockDim.x + threadIdx.x;
    if (idx >= IN * HID) return;
    int j = idx & 7, lane = (idx >> 3) & 63, tt = idx >> 9;
    int kt = tt % KT, ct = tt / KT;
    int k = kt * 32 + (lane >> 4) * 8 + j;
    int c = ct * 16 + (lane & 15);
    rf[idx] = f2bf(root[k * HID + c]);
}

__global__ void k_count(const int* __restrict__ dst, const int* __restrict__ etype,
                        float* __restrict__ cnt) {
    int e = blockIdx.x * blockDim.x + threadIdx.x;
    if (e >= N_EDGES) return;
    atomicAdd(&cnt[(size_t)dst[e] * N_REL + etype[e]], 1.0f);
}

// degree per node + IN-PLACE cnt -> 1/max(cnt,1)
__global__ void k_deg_inv(float* __restrict__ cnt, int* __restrict__ hist) {
    int n = blockIdx.x * blockDim.x + threadIdx.x;
    if (n >= N_NODES) return;
    float* row = cnt + (size_t)n * N_REL;
    float s = 0.f;
#pragma unroll 8
    for (int r = 0; r < N_REL; ++r) {
        float c = row[r];
        s += c;
        row[r] = 1.0f / fmaxf(c, 1.0f);
    }
    hist[n] = (int)(s + 0.5f);
}

// exclusive scan over N_NODES entries, po_d[N]=E
__global__ void k_scan_d(const int* __restrict__ hist, int* __restrict__ po) {
    __shared__ int csum[256];
    int t = threadIdx.x;
    const int CH = (N_NODES + 255) / 256;
    int k0 = t * CH, k1 = min(k0 + CH, N_NODES);
    int s = 0;
    for (int k = k0; k < k1; ++k) s += hist[k];
    csum[t] = s;
    __syncthreads();
    if (t == 0) {
        int acc = 0;
        for (int i = 0; i < 256; ++i) { int v = csum[i]; csum[i] = acc; acc += v; }
        po[N_NODES] = acc;
    }
    __syncthreads();
    int base = csum[t];
    for (int k = k0; k < k1; ++k) { po[k] = base; base += hist[k]; }
}

// (chunk, rel) histogram with LDS aggregation (runtime chunk size)
__global__ void k_hist_cr(const int* __restrict__ dst, const int* __restrict__ etype,
                          int* __restrict__ hist, int chn, int nkeyc) {
    __shared__ int lh[NKEYC_MAX];
    int t = threadIdx.x;
    if (t < nkeyc) lh[t] = 0;
    __syncthreads();
    int e = blockIdx.x * blockDim.x + t;
    if (e < N_EDGES) atomicAdd(&lh[(dst[e] / chn) * N_REL + etype[e]], 1);
    __syncthreads();
    if (t < nkeyc && lh[t]) atomicAdd(&hist[t], lh[t]);
}

// scan nkeyc buckets, each padded to a multiple of 256
__global__ void k_scan_cr(const int* __restrict__ hist, int* __restrict__ po, int nkeyc) {
    if (threadIdx.x == 0) {
        int acc = 0;
        for (int k = 0; k < nkeyc; ++k) {
            po[k] = acc;
            acc += ((hist[k] + 255) >> 8) << 8;
        }
        po[nkeyc] = acc;
    }
}

// init streams: pads -> dump row
__global__ void k_fill(int* __restrict__ ps_src, int* __restrict__ ps_os,
                       int* __restrict__ ps_dst, int dumprow) {
    for (size_t s = (size_t)blockIdx.x * blockDim.x + threadIdx.x; s < PERM_CAP;
         s += (size_t)gridDim.x * blockDim.x) {
        ps_src[s] = 0;
        ps_os[s] = dumprow;
        ps_dst[s] = 0;
    }
}

// block-aggregated scatter into (chunk,rel)-major slots + dst-major oslot.
// No cnt gather (moved to k_msg as invcnt lookup).
__global__ void k_scatter_s(const int* __restrict__ src, const int* __restrict__ dst,
                            const int* __restrict__ etype,
                            const int* __restrict__ po_cr, int* __restrict__ cur_cr,
                            const int* __restrict__ po_d, int* __restrict__ cur_d,
                            int* __restrict__ ps_src, int* __restrict__ ps_os,
                            int* __restrict__ ps_dst, int chn, int nkeyc) {
    __shared__ int lh[NKEYC_MAX], sbase[NKEYC_MAX];
    int t = threadIdx.x;  // 256
    if (t < nkeyc) lh[t] = 0;
    __syncthreads();
    int e0 = blockIdx.x * SP_EPB;
    int e_[4], key_[4];
#pragma unroll
    for (int i = 0; i < 4; ++i) {
        int e = e0 + t + i * 256;
        e_[i] = e;
        if (e < N_EDGES) {
            key_[i] = (dst[e] / chn) * N_REL + etype[e];
            atomicAdd(&lh[key_[i]], 1);
        }
    }
    __syncthreads();
    if (t < nkeyc) { if (lh[t]) sbase[t] = atomicAdd(&cur_cr[t], lh[t]); lh[t] = 0; }
    __syncthreads();
#pragma unroll
    for (int i = 0; i < 4; ++i) {
        if (e_[i] < N_EDGES) {
            int e = e_[i], key = key_[i];
            int d = dst[e];
            int p = atomicAdd(&lh[key], 1);
            int slot = po_cr[key] + sbase[key] + p;
            int os_g = po_d[d] + atomicAdd(&cur_d[d], 1);
            int os_l = os_g - po_d[(d / chn) * chn];   // chunk-local pm row
            ps_src[slot] = src[e];
            ps_os[slot] = os_l;
            ps_dst[slot] = d;
        }
    }
}

// ---- MFMA root GEMM: h[n] = bias + hb[n] @ root ----
template <int IN, int KT>
__global__ __launch_bounds__(256, 4)
void k_rootgemm(const unsigned short* __restrict__ hb_in,
                const unsigned short* __restrict__ rf,
                const float* __restrict__ bias, float* __restrict__ h) {
    __shared__ unsigned short Wl[8 * KT * 64 * 8];
    {
        const f32x4* Wg = (const f32x4*)rf;
        f32x4* Wd = (f32x4*)Wl;
        for (int kk = threadIdx.x; kk < 8 * KT * 64; kk += 256) Wd[kk] = Wg[kk];
    }
    __syncthreads();

    int l = threadIdx.x & 63, wv = threadIdx.x >> 6;
    int lrow = l & 15, lk = l >> 4;
    int nbase = blockIdx.x * 64 + wv * 16;

    int nrow = min(nbase + lrow, N_NODES - 1);
    bf16x8 a[KT];
    const unsigned short* hrow = hb_in + (size_t)nrow * IN + lk * 8;
#pragma unroll
    for (int kt = 0; kt < KT; ++kt)
        a[kt] = *(const bf16x8*)(hrow + kt * 32);

    f32x4 acc[8];
#pragma unroll
    for (int ct = 0; ct < 8; ++ct) acc[ct] = (f32x4){0.f, 0.f, 0.f, 0.f};
#pragma unroll
    for (int ct = 0; ct < 8; ++ct) {
#pragma unroll
        for (int kt = 0; kt < KT; ++kt) {
            bf16x8 bb = *(const bf16x8*)(Wl + ((ct * KT + kt) * 64 + l) * 8);
            acc[ct] = __builtin_amdgcn_mfma_f32_16x16x32_bf16(a[kt], bb, acc[ct], 0, 0, 0);
        }
    }
#pragma unroll
    for (int q = 0; q < 4; ++q) {
        int n = nbase + lk * 4 + q;
        if (n < N_NODES) {
#pragma unroll
            for (int ct = 0; ct < 8; ++ct)
                h[(size_t)n * HID + ct * 16 + lrow] = acc[ct][q] + bias[ct * 16 + lrow];
        }
    }
}

// ---- Phase A: rel-major MFMA message kernel (plain stores) ----
// inv gathered here from in-place invcnt (r uniform per block)
template <int IN, int KT>
__global__ __launch_bounds__(256, 4)
void k_msg(const unsigned short* __restrict__ hb_in, const int* __restrict__ ps_src,
           const int* __restrict__ ps_os, const int* __restrict__ ps_dst,
           const float* __restrict__ invc,
           const int* __restrict__ po_cr,   // 41 entries for this chunk
           const unsigned short* __restrict__ Wf, unsigned int* __restrict__ pm) {
    __shared__ unsigned short Wl[8 * KT * 64 * 8];
    int slot0 = po_cr[0] + blockIdx.x * 256;
    if (slot0 >= po_cr[N_REL]) return;
    int r = 0;
    while (po_cr[r + 1] <= slot0) ++r;

    {   // stage W_r fragments -> LDS
        const f32x4* Wg = (const f32x4*)(Wf + (size_t)r * (8 * KT * 64 * 8));
        f32x4* Wd = (f32x4*)Wl;
        for (int kk = threadIdx.x; kk < 8 * KT * 64; kk += 256) Wd[kk] = Wg[kk];
    }
    __syncthreads();

    int l = threadIdx.x & 63, wv = threadIdx.x >> 6;
    int lrow = l & 15, lk = l >> 4;

    for (int t = wv; t < 16; t += 4) {
        int slot = slot0 + t * 16 + lrow;
        int sv = ps_src[slot];
        int os = ps_os[slot];
        int d  = ps_dst[slot];
        float inv = invc[(size_t)d * N_REL + r];

        bf16x8 a[KT];
        const unsigned short* hrow = hb_in + (size_t)sv * IN + lk * 8;
#pragma unroll
        for (int kt = 0; kt < KT; ++kt)
            a[kt] = *(const bf16x8*)(hrow + kt * 32);

        f32x4 acc[8];
#pragma unroll
        for (int ct = 0; ct < 8; ++ct) acc[ct] = (f32x4){0.f, 0.f, 0.f, 0.f};
#pragma unroll
        for (int ct = 0; ct < 8; ++ct) {
#pragma unroll
            for (int kt = 0; kt < KT; ++kt) {
                bf16x8 bb = *(const bf16x8*)(Wl + ((ct * KT + kt) * 64 + l) * 8);
                acc[ct] = __builtin_amdgcn_mfma_f32_16x16x32_bf16(a[kt], bb, acc[ct], 0, 0, 0);
            }
        }
        // scaled bf16-pack store: per (q,cp) one 64B line per 16-lane group
#pragma unroll
        for (int q = 0; q < 4; ++q) {
            int row = lk * 4 + q;
            int osq   = __shfl(os, row);
            float ivq = __shfl(inv, row);
            unsigned int* dp = pm + (size_t)osq * 64 + lrow;
#pragma unroll
            for (int cp = 0; cp < 4; ++cp) {
                unsigned int u = (unsigned int)f2bf(acc[2 * cp][q] * ivq)
                               | ((unsigned int)f2bf(acc[2 * cp + 1][q] * ivq) << 16);
                dp[cp * 16] = u;
            }
        }
    }
}

// ---- Phase B: dst-major streaming reduce ----
template <bool WRITE_HB>
__global__ __launch_bounds__(256, 8)
void k_reduce(const unsigned int* __restrict__ pm, const int* __restrict__ po_d,
              int n0chunk, int chn, float* __restrict__ h,
              unsigned short* __restrict__ hb_out) {
    int wv = threadIdx.x >> 6, p = threadIdx.x & 63;
    int n = n0chunk + blockIdx.x * 4 + wv;
    if (n >= n0chunk + chn) return;
    int pmbase = po_d[n0chunk];
    int b0 = po_d[n] - pmbase;
    int cn = po_d[n + 1] - pmbase - b0;
    float lo = 0.f, hi = 0.f;
    const unsigned int* rp = pm + (size_t)b0 * 64 + p;
    int k = 0;
    for (; k + 4 <= cn; k += 4) {
        unsigned int u0 = rp[0], u1 = rp[64], u2 = rp[128], u3 = rp[192];
        rp += 256;
        lo += bflo(u0) + bflo(u1) + bflo(u2) + bflo(u3);
        hi += bfhi(u0) + bfhi(u1) + bfhi(u2) + bfhi(u3);
    }
    for (; k < cn; ++k) {
        unsigned int u = rp[0];
        rp += 64;
        lo += bflo(u); hi += bfhi(u);
    }
    int cA = (p & 15) + 32 * (p >> 4);
    float* hp = h + (size_t)n * HID;
    float vA = fmaxf(hp[cA] + lo, 0.f);
    float vB = fmaxf(hp[cA + 16] + hi, 0.f);
    hp[cA] = vA;
    hp[cA + 16] = vB;
    if (WRITE_HB) {
        hb_out[(size_t)n * HID + cA] = f2bf(vA);
        hb_out[(size_t)n * HID + cA + 16] = f2bf(vB);
    }
}

// layer-1 A source: hb1[n][:] = bf16(node_emb[x[n]][:])
__global__ void k_cvt_emb(const float* __restrict__ emb, const int* __restrict__ x,
                          unsigned short* __restrict__ hb) {
    int idx = blockIdx.x * blockDim.x + threadIdx.x;
    if (idx >= N_NODES * (EMB / 4)) return;
    int n = idx / (EMB / 4), c4 = idx % (EMB / 4);
    int row = x[n];
    float4 v = *(const float4*)(emb + (size_t)row * EMB + c4 * 4);
    ushort4 o = {f2bf(v.x), f2bf(v.y), f2bf(v.z), f2bf(v.w)};
    *(ushort4*)(hb + (size_t)n * EMB + c4 * 4) = o;
}

__global__ void k_gcount2(const int* __restrict__ batch, float* __restrict__ cntG) {
    int g = threadIdx.x;
    if (g >= N_GRAPHS) return;
    int lo = 0, hi = N_NODES;
    while (lo < hi) { int m = (lo + hi) >> 1; if (batch[m] < g) lo = m + 1; else hi = m; }
    int lb0 = lo;
    lo = 0; hi = N_NODES;
    while (lo < hi) { int m = (lo + hi) >> 1; if (batch[m] < g + 1) lo = m + 1; else hi = m; }
    cntG[g] = (float)(lo - lb0);
}

__global__ void k_pool(const float* __restrict__ h, const int* __restrict__ batch,
                       float* __restrict__ acc) {
    const int CH = 64;
    int n0 = blockIdx.x * CH;
    int o = threadIdx.x;  // 128
    int nend = min(n0 + CH, N_NODES);
    if (n0 >= N_NODES) return;
    int curg = batch[n0];
    float run = 0.f;
    for (int n = n0; n < nend; ++n) {
        int g = batch[n];
        if (g != curg) {
            atomicAdd(&acc[(size_t)curg * HID + o], run);
            run = 0.f;
            curg = g;
        }
        run += h[(size_t)n * HID + o];
    }
    atomicAdd(&acc[(size_t)curg * HID + o], run);
}

__global__ void k_final(const float* __restrict__ acc, const float* __restrict__ cntG,
                        float* __restrict__ out) {
    int idx = blockIdx.x * blockDim.x + threadIdx.x;
    if (idx >= N_GRAPHS * HID) return;
    int g = idx >> 7;
    out[idx] = acc[idx] / fmaxf(cntG[g], 1.0f);
}

extern "C" void kernel_launch(void* const* d_in, const int* in_sizes, int n_in,
                              void* d_out, int out_size, void* d_ws, size_t ws_size,
                              hipStream_t stream) {
    const int*   x         = (const int*)d_in[0];
    const int*   edge_index= (const int*)d_in[1];
    const int*   etype     = (const int*)d_in[2];
    const int*   batch     = (const int*)d_in[3];
    const float* node_emb  = (const float*)d_in[4];
    const float* comp1     = (const float*)d_in[5];
    const float* basis1    = (const float*)d_in[6];
    const float* root1     = (const float*)d_in[7];
    const float* bias1     = (const float*)d_in[8];
    const float* comp2     = (const float*)d_in[9];
    const float* basis2    = (const float*)d_in[10];
    const float* root2     = (const float*)d_in[11];
    const float* bias2     = (const float*)d_in[12];
    float* out = (float*)d_out;

    const int* src = edge_index;
    const int* dst = edge_index + N_EDGES;

    float* ws = (float*)d_ws;
    unsigned short* Wf1 = (unsigned short*)(ws + OFF_WF1);
    unsigned short* Wf2 = (unsigned short*)(ws + OFF_WF2);
    float* cnt  = ws + OFF_CNT;                      // becomes invcnt in place
    float* h1   = ws + OFF_H1;
    float* h2   = ws + OFF_H2;
    unsigned short* hb1 = (unsigned short*)(ws + OFF_HB1);
    unsigned short* hb2 = (unsigned short*)(ws + OFF_HB2);
    float* cntG = ws + OFF_CNTG;
    float* pool = ws + OFF_POOL;
    int*   ps_src = (int*)(ws + OFF_PSRC);
    int*   ps_os  = (int*)(ws + OFF_POS);
    int*   ps_dst = (int*)(ws + OFF_PDST);
    int*   hist_cr = (int*)(ws + OFF_HCR);
    int*   cur_cr  = (int*)(ws + OFF_CCR);
    int*   po_cr   = (int*)(ws + OFF_POCR);
    int*   hist_d  = (int*)(ws + OFF_HD);
    int*   cur_d   = (int*)(ws + OFF_CD);
    int*   po_d    = (int*)(ws + OFF_POD);
    unsigned short* rf1 = (unsigned short*)(ws + OFF_RF1);
    unsigned short* rf2 = (unsigned short*)(ws + OFF_RF2);
    unsigned int* pm = (unsigned int*)(ws + OFF_PM);

    // ---- choose chunk count from workspace size (deterministic) ----
    size_t ws_floats = ws_size / sizeof(float);
    int nch = 4;
    if (ws_floats >= OFF_PM + ((size_t)N_EDGES / 1 + 12504) * 64) nch = 1;
    else if (ws_floats >= OFF_PM + ((size_t)N_EDGES / 2 + 12504) * 64) nch = 2;
    int chn = N_NODES / nch;
    int nkeyc = nch * N_REL;
    int capr = N_EDGES / nch + 12504;
    int gridm = (capr + 255) / 256 + N_REL;          // k_msg grid (early-exit covers)

    hipMemsetAsync(cnt, 0, (size_t)N_NODES * N_REL * sizeof(float), stream);
    hipMemsetAsync(cntG, 0, (size_t)(N_GRAPHS + N_GRAPHS * HID) * sizeof(float), stream);
    hipMemsetAsync(hist_cr, 0, 2 * NKEYC_MAX * sizeof(int), stream);   // hist_cr + cur_cr
    hipMemsetAsync(cur_d, 0, N_NODES * sizeof(int), stream);

    // ---- prep (serves both layers) ----
    k_count<<<(N_EDGES + 255) / 256, 256, 0, stream>>>(dst, etype, cnt);
    k_deg_inv<<<(N_NODES + 255) / 256, 256, 0, stream>>>(cnt, hist_d);
    k_scan_d<<<1, 256, 0, stream>>>(hist_d, po_d);
    k_hist_cr<<<(N_EDGES + 255) / 256, 256, 0, stream>>>(dst, etype, hist_cr, chn, nkeyc);
    k_scan_cr<<<1, 64, 0, stream>>>(hist_cr, po_cr, nkeyc);
    k_fill<<<2048, 256, 0, stream>>>(ps_src, ps_os, ps_dst, capr - 1);
    k_scatter_s<<<(N_EDGES + SP_EPB - 1) / SP_EPB, 256, 0, stream>>>(
        src, dst, etype, po_cr, cur_cr, po_d, cur_d, ps_src, ps_os, ps_dst, chn, nkeyc);

    // fragment-ordered bf16 weights + root matrices
    k_Wfrag<EMB, 2><<<(N_REL * EMB * HID + 255) / 256, 256, 0, stream>>>(comp1, basis1, Wf1);
    k_Wfrag<HID, 4><<<(N_REL * HID * HID + 255) / 256, 256, 0, stream>>>(comp2, basis2, Wf2);
    k_rootfrag<EMB, 2><<<(EMB * HID + 255) / 256, 256, 0, stream>>>(root1, rf1);
    k_rootfrag<HID, 4><<<(HID * HID + 255) / 256, 256, 0, stream>>>(root2, rf2);

    // ---- layer 1 ----
    k_cvt_emb<<<(N_NODES * (EMB / 4) + 255) / 256, 256, 0, stream>>>(node_emb, x, hb1);
    k_rootgemm<EMB, 2><<<(N_NODES + 63) / 64, 256, 0, stream>>>(hb1, rf1, bias1, h1);
    for (int c = 0; c < nch; ++c) {
        k_msg<EMB, 2><<<gridm, 256, 0, stream>>>(hb1, ps_src, ps_os, ps_dst, cnt,
                                                 po_cr + c * N_REL, Wf1, pm);
        k_reduce<true><<<chn / 4, 256, 0, stream>>>(pm, po_d, c * chn, chn, h1, hb2);
    }

    // ---- layer 2 ----
    k_rootgemm<HID, 4><<<(N_NODES + 63) / 64, 256, 0, stream>>>(hb2, rf2, bias2, h2);
    for (int c = 0; c < nch; ++c) {
        k_msg<HID, 4><<<gridm, 256, 0, stream>>>(hb2, ps_src, ps_os, ps_dst, cnt,
                                                 po_cr + c * N_REL, Wf2, pm);
        k_reduce<false><<<chn / 4, 256, 0, stream>>>(pm, po_d, c * chn, chn, h2, nullptr);
    }

    // ---- global mean pool ----
    k_gcount2<<<1, 64, 0, stream>>>(batch, cntG);
    k_pool<<<(N_NODES + 63) / 64, HID, 0, stream>>>(h2, batch, pool);
    k_final<<<(N_GRAPHS * HID + 255) / 256, 256, 0, stream>>>(pool, cntG, out);
}